// Round 7
// baseline (476.237 us; speedup 1.0000x reference)
//
#include <hip/hip_runtime.h>

// RoIAlign multi-level extractor (FPN), matches jax reference:
//   K=1024 rois, C=256, OUT=7, SR=2, levels strides {4,8,16,32}, B=2
//
// v3.1: rect-staged design (fixes v2's vector-memory transaction bound).
//   Kernel A (K threads): per-roi metadata -> d_ws. Level (double-log2 exact),
//     batch offset, rect origin (x0,y0) + dims (W_f,H_f), and rect-LOCAL
//     per-axis corner indices (y premultiplied by W_f), fracs, valid flags.
//   Kernel B (grid K*8 x 256): block = (roi, 32-channel chunk), 8 iters of 4
//     channels. Each wave stages one channel's rect with row-contiguous
//     coalesced loads into LDS (20 KB -> 8 blocks/CU), then 196 threads
//     compute 4x49 outputs via 16-corner bilinear from LDS. Coalesced store.
//   RECTMAX=1280: derived bound for rect area is ~1040 floats (worst case at
//     the lvl-0 boundary with clip-induced extreme aspect: a*b<784, a<=196,
//     area<=(0.929a+2)(0.929b+2)); 1024 was NOT safe, 1280 has margin.
//   Fallback: verified v1 block-per-roi kernel if ws too small.

#define CCH 256
#define NS  14    // OUT*SR samples per axis
#define NG  28
#define MSTRIDE 128   // ints per roi in metadata table
#define RECTMAX 1280  // max rect floats per channel (bound ~1040, see above)

// ---------------- Kernel A: per-roi metadata ----------------
__global__ __launch_bounds__(256) void roi_meta_kernel(
    const float* __restrict__ rois, int* __restrict__ meta, int K)
{
  const int k = blockIdx.x * 256 + threadIdx.x;
  if (k >= K) return;

  const float r0 = rois[k*5 + 0];
  const float x1 = rois[k*5 + 1], y1 = rois[k*5 + 2];
  const float x2 = rois[k*5 + 3], y2 = rois[k*5 + 4];

  // level: clip(floor(log2(sqrt(w*h)/56 + 1e-6)), 0, 3); f32 op-by-op,
  // log2 via double (matches np.log2 f32 at the binning step boundaries)
  const float scl = __fsqrt_rn(__fmul_rn(__fsub_rn(x2, x1), __fsub_rn(y2, y1)));
  const float tq  = __fadd_rn(__fdiv_rn(scl, 56.0f), 1e-6f);
  const float lg  = (float)log2((double)tq);
  int lvl = (int)floorf(lg);
  lvl = lvl < 0 ? 0 : (lvl > 3 ? 3 : lvl);

  const int   sizeL = 256 >> lvl;
  const float ssc   = 1.0f / (float)(4 << lvl);

  int* m = meta + (size_t)k * MSTRIDE;
  float* mf = (float*)m;
  m[0] = lvl;
  m[1] = (int)r0 * CCH * sizeL * sizeL;

  int x0 = 0, y0 = 0, wf = 1;

  #pragma unroll
  for (int axis = 0; axis < 2; ++axis) {
    const float c1 = axis ? y1 : x1;
    const float c2 = axis ? y2 : x2;
    const float start = __fsub_rn(__fmul_rn(c1, ssc), 0.5f);
    const float rlen  = __fmul_rn(__fsub_rn(c2, c1), ssc);
    const float bwid  = __fdiv_rn(rlen, 7.0f);

    // pass 1: rect bounds for this axis
    int mn = sizeL - 1, mx = 0;
    for (int s = 0; s < NS; ++s) {
      const int bin = s >> 1, i = s & 1;
      const float off = ((float)i + 0.5f) * 0.5f;
      const float g = __fadd_rn(__fadd_rn(start, __fmul_rn((float)bin, bwid)),
                                __fmul_rn(off, bwid));
      float cc = fminf(fmaxf(g, 0.0f), (float)(sizeL - 1));
      const int lo0 = (int)floorf(cc);
      const int lo = (lo0 >= sizeL - 1) ? sizeL - 1 : lo0;
      const int hi = (lo0 >= sizeL - 1) ? sizeL - 1 : lo0 + 1;
      mn = lo < mn ? lo : mn;
      mx = hi > mx ? hi : mx;
    }
    const int o0 = mn;
    const int ext = mx - mn + 1;
    if (axis == 0) { x0 = o0; wf = ext; m[2] = o0; m[4] = ext; }
    else           { y0 = o0; m[3] = o0; m[5] = ext; }

    // pass 2: rect-local corner data
    for (int s = 0; s < NS; ++s) {
      const int bin = s >> 1, i = s & 1;
      const float off = ((float)i + 0.5f) * 0.5f;
      const float g = __fadd_rn(__fadd_rn(start, __fmul_rn((float)bin, bwid)),
                                __fmul_rn(off, bwid));
      const float valid = (g >= -1.0f && g <= (float)sizeL) ? 1.0f : 0.0f;
      float cc = fminf(fmaxf(g, 0.0f), (float)(sizeL - 1));
      const int lo0 = (int)floorf(cc);
      int lo, hi; float frac;
      if (lo0 >= sizeL - 1) { lo = sizeL - 1; hi = sizeL - 1; frac = 0.0f; }
      else                  { lo = lo0; hi = lo0 + 1; frac = cc - (float)lo0; }
      if (axis == 0) {
        m[8 + s]  = lo - x0;  m[22 + s] = hi - x0;
        mf[64 + s] = frac; mf[78 + s] = valid;
      } else {
        m[36 + s] = (lo - y0) * wf; m[50 + s] = (hi - y0) * wf;
        mf[92 + s] = frac; mf[106 + s] = valid;
      }
    }
  }
}

// ---------------- Kernel B: rect-staged bilinear ----------------
__global__ __launch_bounds__(256, 8) void roi_rect_kernel(
    const float* __restrict__ f0, const float* __restrict__ f1,
    const float* __restrict__ f2, const float* __restrict__ f3,
    const int* __restrict__ meta, float* __restrict__ out)
{
  const int k     = blockIdx.x >> 3;   // roi
  const int chunk = blockIdx.x & 7;    // 32-channel chunk
  const int t     = threadIdx.x;
  const int w     = t >> 6;            // wave 0..3
  const int lane  = t & 63;

  __shared__ float s_rect[4][RECTMAX];

  const int* m = meta + (size_t)k * MSTRIDE;
  const float* mf = (const float*)m;
  const int lvl  = m[0];
  const int boff = m[1];
  const int x0   = m[2], y0 = m[3];
  const int W_f  = m[4], H_f = m[5];
  const float* fp = (lvl == 0) ? f0 : (lvl == 1) ? f1 : (lvl == 2) ? f2 : f3;
  const int sz = 256 >> lvl;
  const int HW = sz * sz;

  // compute-phase decode (threads 0..195): cs = o/49, bin = o%49
  const int o   = t;
  const int cs  = o / 49;
  const int bin = o - cs * 49;
  const int ph  = bin / 7;
  const int pw  = bin - ph * 7;

  const int HWf = H_f * W_f;   // <= ~1040 < RECTMAX by derivation
  const int lim = HWf > RECTMAX ? RECTMAX : HWf;

  for (int it = 0; it < 8; ++it) {
    const int c0 = chunk * 32 + it * 4;

    // stage: wave w -> channel c0+w rect, row-contiguous coalesced loads
    {
      const float* src = fp + boff + (size_t)(c0 + w) * HW
                       + (size_t)y0 * sz + x0;
      float* dst = s_rect[w];
      int ro = 0;
      long go = 0;
      for (int row = 0; row < H_f; ++row, ro += W_f, go += sz) {
        for (int x = lane; x < W_f; x += 64) {
          const int d = ro + x;
          if (d < lim) dst[d] = src[go + x];
        }
      }
    }
    __syncthreads();

    if (o < 196) {
      const float* rp = s_rect[cs];
      float acc = 0.0f;
      #pragma unroll
      for (int i = 0; i < 2; ++i) {
        const int sy = 2 * ph + i;
        const int yol = m[36 + sy], yoh = m[50 + sy];
        const float fy = mf[92 + sy], vy = mf[106 + sy];
        #pragma unroll
        for (int j = 0; j < 2; ++j) {
          const int sx = 2 * pw + j;
          const int xl = m[8 + sx], xh = m[22 + sx];
          const float fx = mf[64 + sx], vx = mf[78 + sx];
          const float g00 = rp[yol + xl];
          const float g01 = rp[yol + xh];
          const float g10 = rp[yoh + xl];
          const float g11 = rp[yoh + xh];
          const float sval = (1.0f - fy) * ((1.0f - fx) * g00 + fx * g01)
                           + fy * ((1.0f - fx) * g10 + fx * g11);
          acc += sval * (vy * vx);
        }
      }
      out[((size_t)k * CCH + c0 + cs) * 49 + bin] = acc * 0.25f;
    }
    __syncthreads();
  }
}

// ---------------- v1 fallback (verified): block per roi ----------------
__global__ __launch_bounds__(256) void roi_extract_kernel(
    const float* __restrict__ f0, const float* __restrict__ f1,
    const float* __restrict__ f2, const float* __restrict__ f3,
    const float* __restrict__ rois, float* __restrict__ out, int K)
{
  const int k = blockIdx.x;
  const int t = threadIdx.x;

  __shared__ int   s_xidx[NG];
  __shared__ int   s_yoff[NG];
  __shared__ float s_fx[NS], s_vx[NS], s_fy[NS], s_vy[NS];
  __shared__ int   s_lvl, s_boff;
  __shared__ float s_grid[8][NG][NG + 1];

  if (t < NG) {
    const float r0 = rois[k*5 + 0];
    const float x1 = rois[k*5 + 1], y1 = rois[k*5 + 2];
    const float x2 = rois[k*5 + 3], y2 = rois[k*5 + 4];
    const float scl = __fsqrt_rn(__fmul_rn(__fsub_rn(x2, x1), __fsub_rn(y2, y1)));
    const float tq  = __fadd_rn(__fdiv_rn(scl, 56.0f), 1e-6f);
    const float lg  = (float)log2((double)tq);
    int lvl = (int)floorf(lg);
    lvl = lvl < 0 ? 0 : (lvl > 3 ? 3 : lvl);
    const int   sizeL = 256 >> lvl;
    const float ssc   = 1.0f / (float)(4 << lvl);
    const int axis = t / NS;
    const int s    = t - axis*NS;
    const float c1 = axis ? y1 : x1;
    const float c2 = axis ? y2 : x2;
    const float start = __fsub_rn(__fmul_rn(c1, ssc), 0.5f);
    const float rlen  = __fmul_rn(__fsub_rn(c2, c1), ssc);
    const float bwid  = __fdiv_rn(rlen, 7.0f);
    const int bin = s >> 1, i = s & 1;
    const float off = ((float)i + 0.5f) * 0.5f;
    const float g = __fadd_rn(__fadd_rn(start, __fmul_rn((float)bin, bwid)),
                              __fmul_rn(off, bwid));
    const float valid = (g >= -1.0f && g <= (float)sizeL) ? 1.0f : 0.0f;
    float cc = fminf(fmaxf(g, 0.0f), (float)(sizeL - 1));
    const int lo0 = (int)floorf(cc);
    int lo, hi; float frac;
    if (lo0 >= sizeL - 1) { lo = sizeL - 1; hi = sizeL - 1; frac = 0.0f; }
    else                  { lo = lo0; hi = lo0 + 1; frac = cc - (float)lo0; }
    if (axis == 0) { s_xidx[s] = lo; s_xidx[NS + s] = hi; s_fx[s] = frac; s_vx[s] = valid; }
    else           { s_yoff[s] = lo * sizeL; s_yoff[NS + s] = hi * sizeL;
                     s_fy[s] = frac; s_vy[s] = valid; }
    if (t == 0) { s_lvl = lvl; s_boff = (int)r0 * CCH * sizeL * sizeL; }
  }
  __syncthreads();

  const int lvl = s_lvl;
  const float* fp = (lvl == 0) ? f0 : (lvl == 1) ? f1 : (lvl == 2) ? f2 : f3;
  const int sz = 256 >> lvl;
  const int HW = sz * sz;
  const float* bp = fp + s_boff;
  const int csub = t >> 5;
  const int lane = t & 31;
  const int xo   = (lane < NG) ? s_xidx[lane] : 0;

  for (int cg = 0; cg < CCH / 8; ++cg) {
    const int c0 = cg * 8;
    const float* cp = bp + (size_t)(c0 + csub) * HW;
    if (lane < NG) {
      #pragma unroll
      for (int r = 0; r < NG; ++r) s_grid[csub][r][lane] = cp[s_yoff[r] + xo];
    }
    __syncthreads();
    for (int o = t; o < 8 * 49; o += 256) {
      const int cs  = o / 49;
      const int bin = o - cs * 49;
      const int ph  = bin / 7, pw = bin - ph * 7;
      float acc = 0.0f;
      #pragma unroll
      for (int i = 0; i < 2; ++i) {
        const int sy = 2 * ph + i;
        const float fy = s_fy[sy], vy = s_vy[sy];
        #pragma unroll
        for (int j = 0; j < 2; ++j) {
          const int sx = 2 * pw + j;
          const float fx = s_fx[sx], vx = s_vx[sx];
          const float g00 = s_grid[cs][sy][sx];
          const float g01 = s_grid[cs][sy][NS + sx];
          const float g10 = s_grid[cs][NS + sy][sx];
          const float g11 = s_grid[cs][NS + sy][NS + sx];
          const float sval = (1.0f - fy) * ((1.0f - fx) * g00 + fx * g01)
                           + fy * ((1.0f - fx) * g10 + fx * g11);
          acc += sval * (vy * vx);
        }
      }
      out[((size_t)k * CCH + c0 + cs) * 49 + bin] = acc * 0.25f;
    }
    __syncthreads();
  }
}

extern "C" void kernel_launch(void* const* d_in, const int* in_sizes, int n_in,
                              void* d_out, int out_size, void* d_ws, size_t ws_size,
                              hipStream_t stream) {
  const float* f0   = (const float*)d_in[0];
  const float* f1   = (const float*)d_in[1];
  const float* f2   = (const float*)d_in[2];
  const float* f3   = (const float*)d_in[3];
  const float* rois = (const float*)d_in[4];
  float* out = (float*)d_out;
  const int K = in_sizes[4] / 5;

  const size_t need = (size_t)K * MSTRIDE * sizeof(int);
  if (ws_size >= need) {
    int* meta = (int*)d_ws;
    hipLaunchKernelGGL(roi_meta_kernel, dim3((K + 255) / 256), dim3(256), 0, stream,
                       rois, meta, K);
    hipLaunchKernelGGL(roi_rect_kernel, dim3(K * 8), dim3(256), 0, stream,
                       f0, f1, f2, f3, meta, out);
  } else {
    hipLaunchKernelGGL(roi_extract_kernel, dim3(K), dim3(256), 0, stream,
                       f0, f1, f2, f3, rois, out, K);
  }
}

// Round 8
// 105.968 us; speedup vs baseline: 4.4942x; 4.4942x over previous
//
#include <hip/hip_runtime.h>

// RoIAlign multi-level extractor (FPN), matches jax reference:
//   K=1024 rois, C=256, OUT=7, SR=2, levels strides {4,8,16,32}, B=2
//
// v4 = v1 (verified 180us) with 8x more blocks for TLP.
//   v1 diagnosis: 1024 blocks, occ 28%, all pipes <25% -> latency-bound,
//   nothing overlaps the per-iteration stage->barrier->compute chain.
//   v4: grid = K*8, block = (roi, 32-channel chunk), 4 iterations of 8
//   channels. Same staging pattern (28 unrolled row loads, half-wave per
//   channel), same compute. LDS 26.6KB -> 6 blocks/CU -> ~24 waves/CU.

#define CCH 256
#define NS  14   // OUT*SR samples per axis
#define NG  28   // 2*NS corner rows/cols (lo then hi)

__global__ __launch_bounds__(256) void roi_extract_kernel(
    const float* __restrict__ f0, const float* __restrict__ f1,
    const float* __restrict__ f2, const float* __restrict__ f3,
    const float* __restrict__ rois, float* __restrict__ out, int K)
{
  const int k     = blockIdx.x >> 3;   // roi
  const int chunk = blockIdx.x & 7;    // 32-channel chunk
  const int t     = threadIdx.x;

  __shared__ int   s_xidx[NG];          // x pixel index (lo[0..13], hi[0..13])
  __shared__ int   s_yoff[NG];          // y pixel index * W
  __shared__ float s_fx[NS], s_vx[NS], s_fy[NS], s_vy[NS];
  __shared__ int   s_lvl, s_boff;
  __shared__ float s_grid[8][NG][NG + 1];  // 8 channels x 28x28 corner grid (+1 pad)

  if (t < NG) {
    const float r0 = rois[k*5 + 0];
    const float x1 = rois[k*5 + 1], y1 = rois[k*5 + 2];
    const float x2 = rois[k*5 + 3], y2 = rois[k*5 + 4];

    // level mapping: clip(floor(log2(sqrt(w*h)/56 + 1e-6)), 0, 3)
    // f32 op-by-op (no fma contraction); log2 via double == correctly-rounded
    // f32 log2 (matches np.log2 float32 at the binning step discontinuities)
    const float scl = __fsqrt_rn(__fmul_rn(__fsub_rn(x2, x1), __fsub_rn(y2, y1)));
    const float tq  = __fadd_rn(__fdiv_rn(scl, 56.0f), 1e-6f);
    const float lg  = (float)log2((double)tq);
    int lvl = (int)floorf(lg);
    lvl = lvl < 0 ? 0 : (lvl > 3 ? 3 : lvl);

    const int   sizeL = 256 >> lvl;               // H == W at this level
    const float ssc   = 1.0f / (float)(4 << lvl); // spatial scale

    const int axis = t / NS;       // 0 = x, 1 = y
    const int s    = t - axis*NS;  // sample index 0..13

    const float c1 = axis ? y1 : x1;
    const float c2 = axis ? y2 : x2;
    const float start = __fsub_rn(__fmul_rn(c1, ssc), 0.5f);
    const float rlen  = __fmul_rn(__fsub_rn(c2, c1), ssc);
    const float bwid  = __fdiv_rn(rlen, 7.0f);

    const int bin = s >> 1, i = s & 1;
    const float off = ((float)i + 0.5f) * 0.5f;   // (i+0.5)/SR, exact
    const float g = __fadd_rn(__fadd_rn(start, __fmul_rn((float)bin, bwid)),
                              __fmul_rn(off, bwid));

    const float valid = (g >= -1.0f && g <= (float)sizeL) ? 1.0f : 0.0f;
    float cc = fminf(fmaxf(g, 0.0f), (float)(sizeL - 1));
    const int lo0 = (int)floorf(cc);
    int lo, hi; float frac;
    if (lo0 >= sizeL - 1) { lo = sizeL - 1; hi = sizeL - 1; frac = 0.0f; }
    else                  { lo = lo0; hi = lo0 + 1; frac = cc - (float)lo0; }

    if (axis == 0) { s_xidx[s] = lo; s_xidx[NS + s] = hi; s_fx[s] = frac; s_vx[s] = valid; }
    else           { s_yoff[s] = lo * sizeL; s_yoff[NS + s] = hi * sizeL;
                     s_fy[s] = frac; s_vy[s] = valid; }
    if (t == 0) {
      s_lvl  = lvl;
      s_boff = (int)r0 * CCH * sizeL * sizeL;     // batch offset (elements)
    }
  }
  __syncthreads();

  const int lvl = s_lvl;
  const float* fp = (lvl == 0) ? f0 : (lvl == 1) ? f1 : (lvl == 2) ? f2 : f3;
  const int sz = 256 >> lvl;
  const int HW = sz * sz;
  const float* bp = fp + s_boff;

  const int csub = t >> 5;        // 0..7: channel within group
  const int lane = t & 31;        // 0..31: x-corner lane (28 active)
  const int xo   = (lane < NG) ? s_xidx[lane] : 0;

  for (int cg = 0; cg < 4; ++cg) {
    const int c0 = chunk * 32 + cg * 8;
    const float* cp = bp + (size_t)(c0 + csub) * HW;

    if (lane < NG) {
      #pragma unroll
      for (int r = 0; r < NG; ++r) {
        s_grid[csub][r][lane] = cp[s_yoff[r] + xo];
      }
    }
    __syncthreads();

    for (int o = t; o < 8 * 49; o += 256) {
      const int cs  = o / 49;
      const int bin = o - cs * 49;
      const int ph  = bin / 7, pw = bin - ph * 7;
      float acc = 0.0f;
      #pragma unroll
      for (int i = 0; i < 2; ++i) {
        const int sy = 2 * ph + i;
        const float fy = s_fy[sy], vy = s_vy[sy];
        #pragma unroll
        for (int j = 0; j < 2; ++j) {
          const int sx = 2 * pw + j;
          const float fx = s_fx[sx], vx = s_vx[sx];
          const float g00 = s_grid[cs][sy][sx];
          const float g01 = s_grid[cs][sy][NS + sx];
          const float g10 = s_grid[cs][NS + sy][sx];
          const float g11 = s_grid[cs][NS + sy][NS + sx];
          const float sval = (1.0f - fy) * ((1.0f - fx) * g00 + fx * g01)
                           + fy * ((1.0f - fx) * g10 + fx * g11);
          acc += sval * (vy * vx);
        }
      }
      out[((size_t)k * CCH + c0 + cs) * 49 + bin] = acc * 0.25f;
    }
    __syncthreads();
  }
}

extern "C" void kernel_launch(void* const* d_in, const int* in_sizes, int n_in,
                              void* d_out, int out_size, void* d_ws, size_t ws_size,
                              hipStream_t stream) {
  const float* f0   = (const float*)d_in[0];
  const float* f1   = (const float*)d_in[1];
  const float* f2   = (const float*)d_in[2];
  const float* f3   = (const float*)d_in[3];
  const float* rois = (const float*)d_in[4];
  float* out = (float*)d_out;
  const int K = in_sizes[4] / 5;

  hipLaunchKernelGGL(roi_extract_kernel, dim3(K * 8), dim3(256), 0, stream,
                     f0, f1, f2, f3, rois, out, K);
}

// Round 9
// 95.281 us; speedup vs baseline: 4.9982x; 1.1122x over previous
//
#include <hip/hip_runtime.h>

// RoIAlign multi-level extractor (FPN), matches jax reference.
//   K=1024 rois, C=256, OUT=7, SR=2, strides {4,8,16,32}, B=2
//
// v5: rect-LDS + global_load_lds staging + paired LDS reads.
//   Meta kernel (K threads): exact-fp per-roi metadata incl. contiguous rect
//     [x0,x0+W_f) x [y0,y0+H_f), padded stride Wp=W_f+1 (pad col = edge dup,
//     so capped-x pair reads hit finite staged data; weight is 0 anyway).
//     Rect flat size <= ~1110 floats worst case (extreme-aspect lvl-0 roi:
//     a<=196,b>=4,ab<784 -> (0.929a+3)(0.929b+2) ~ 1110). RECTMAX=1200.
//   Kernel B (grid K*8): block = (roi, 32-ch chunk); 8 iters of 4 channels.
//     Stage: wave w -> channel c0+w via global_load_lds (4B/lane, LDS dest
//     wave-uniform base + lane*4, per-lane global src; 2 rows per load when
//     Wp<=32). No ds_writes, no VGPR round trip.
//     Compute: 196 threads, 1 output each; per sample read adjacent pair
//     (xl, xl+1) -> ds_read2_b32; 8 LDS-read instr/bin vs 16 in v4.
//   LDS 4*1200*4 = 19.2KB -> 8 blocks/CU -> 32 waves/CU.
//   Fallback: v4 kernel (verified 106us) if ws too small.

#define CCH 256
#define NS  14
#define NG  28
#define MSTRIDE 128
#define RECTMAX 1200

__device__ __forceinline__ void gload_lds4(const float* g, float* l) {
  __builtin_amdgcn_global_load_lds(
      (const __attribute__((address_space(1))) void*)g,
      (__attribute__((address_space(3))) void*)l, 4, 0, 0);
}

// ---------------- Kernel A: per-roi metadata ----------------
__global__ __launch_bounds__(256) void roi_meta_kernel(
    const float* __restrict__ rois, int* __restrict__ meta, int K)
{
  const int k = blockIdx.x * 256 + threadIdx.x;
  if (k >= K) return;

  const float r0 = rois[k*5 + 0];
  const float x1 = rois[k*5 + 1], y1 = rois[k*5 + 2];
  const float x2 = rois[k*5 + 3], y2 = rois[k*5 + 4];

  // level: clip(floor(log2(sqrt(w*h)/56 + 1e-6)), 0, 3); f32 op-by-op,
  // log2 via double (matches np.log2 f32 at the binning discontinuities)
  const float scl = __fsqrt_rn(__fmul_rn(__fsub_rn(x2, x1), __fsub_rn(y2, y1)));
  const float tq  = __fadd_rn(__fdiv_rn(scl, 56.0f), 1e-6f);
  const float lg  = (float)log2((double)tq);
  int lvl = (int)floorf(lg);
  lvl = lvl < 0 ? 0 : (lvl > 3 ? 3 : lvl);

  const int   sizeL = 256 >> lvl;
  const float ssc   = 1.0f / (float)(4 << lvl);

  int* m = meta + (size_t)k * MSTRIDE;
  float* mf = (float*)m;
  m[0] = lvl;
  m[1] = (int)r0 * CCH * sizeL * sizeL;

  int lox[NS], hix[NS], loy[NS], hiy[NS];
  float frx[NS], vlx[NS], fry[NS], vly[NS];

  #pragma unroll
  for (int axis = 0; axis < 2; ++axis) {
    const float c1 = axis ? y1 : x1;
    const float c2 = axis ? y2 : x2;
    const float start = __fsub_rn(__fmul_rn(c1, ssc), 0.5f);
    const float rlen  = __fmul_rn(__fsub_rn(c2, c1), ssc);
    const float bwid  = __fdiv_rn(rlen, 7.0f);
    #pragma unroll
    for (int s = 0; s < NS; ++s) {
      const int bin = s >> 1, i = s & 1;
      const float off = ((float)i + 0.5f) * 0.5f;
      const float g = __fadd_rn(__fadd_rn(start, __fmul_rn((float)bin, bwid)),
                                __fmul_rn(off, bwid));
      const float valid = (g >= -1.0f && g <= (float)sizeL) ? 1.0f : 0.0f;
      float cc = fminf(fmaxf(g, 0.0f), (float)(sizeL - 1));
      const int lo0 = (int)floorf(cc);
      int lo, hi; float frac;
      if (lo0 >= sizeL - 1) { lo = sizeL - 1; hi = sizeL - 1; frac = 0.0f; }
      else                  { lo = lo0; hi = lo0 + 1; frac = cc - (float)lo0; }
      if (axis == 0) { lox[s] = lo; hix[s] = hi; frx[s] = frac; vlx[s] = valid; }
      else           { loy[s] = lo; hiy[s] = hi; fry[s] = frac; vly[s] = valid; }
    }
  }

  // g monotone in s -> lo[0] is min, hi[13] is max
  const int x0  = lox[0];
  const int W_f = hix[NS-1] - x0 + 1;
  const int Wp  = W_f + 1;                 // +1 pad col (edge dup)
  const int y0  = loy[0];
  const int H_f = hiy[NS-1] - y0 + 1;

  m[2] = x0; m[3] = y0; m[4] = W_f; m[5] = H_f; m[6] = Wp;

  #pragma unroll
  for (int s = 0; s < NS; ++s) {
    m[8 + s]  = lox[s] - x0;            // rect-local x (pair read at +1)
    m[22 + s] = (loy[s] - y0) * Wp;     // rect-local row offsets
    m[36 + s] = (hiy[s] - y0) * Wp;
    mf[50 + s] = frx[s]; mf[64 + s] = vlx[s];
    mf[78 + s] = fry[s]; mf[92 + s] = vly[s];
  }
}

// ---------------- Kernel B: rect-staged, async staging ----------------
__global__ __launch_bounds__(256) void roi_rect2_kernel(
    const float* __restrict__ f0, const float* __restrict__ f1,
    const float* __restrict__ f2, const float* __restrict__ f3,
    const int* __restrict__ meta, float* __restrict__ out)
{
  const int k     = blockIdx.x >> 3;
  const int chunk = blockIdx.x & 7;
  const int t     = threadIdx.x;
  const int w     = t >> 6;            // wave 0..3 stages channel c0+w
  const int lane  = t & 63;

  __shared__ float s_rect[4][RECTMAX];
  __shared__ int   s_xl[NS], s_ylo[NS], s_yhi[NS];
  __shared__ float s_fx[NS], s_vx[NS], s_fy[NS], s_vy[NS];

  const int* m = meta + (size_t)k * MSTRIDE;
  const float* mf = (const float*)m;
  const int lvl  = m[0];
  const int boff = m[1];
  const int x0   = m[2], y0 = m[3];
  const int W_f  = m[4], H_f = m[5], Wp = m[6];
  const float* fp = (lvl == 0) ? f0 : (lvl == 1) ? f1 : (lvl == 2) ? f2 : f3;
  const int sz = 256 >> lvl;
  const int HW = sz * sz;

  if (t < NS) {
    s_xl[t]  = m[8 + t];
    s_ylo[t] = m[22 + t];
    s_yhi[t] = m[36 + t];
    s_fx[t] = mf[50 + t]; s_vx[t] = mf[64 + t];
    s_fy[t] = mf[78 + t]; s_vy[t] = mf[92 + t];
  }

  // per-lane staging geometry (uniform Wp -> uniform branch)
  const int r_add = (lane >= Wp) ? 1 : 0;       // 2-row packing (Wp<=32)
  const int xx2   = lane - (r_add ? Wp : 0);
  const int gx2   = xx2 < W_f - 1 ? xx2 : W_f - 1;
  const int gx1   = lane < W_f - 1 ? lane : W_f - 1;  // 1-row path clamp

  const int o   = t;                  // compute decode (o < 196)
  const int cs  = o / 49;
  const int bin = o - cs * 49;
  const int ph  = bin / 7;
  const int pw  = bin - ph * 7;

  const float* base = fp + boff + (size_t)y0 * sz + x0;

  for (int it = 0; it < 8; ++it) {
    const int c0 = chunk * 32 + it * 4;
    // ---- stage channel c0+w into s_rect[w] via global_load_lds ----
    {
      const float* src = base + (size_t)(c0 + w) * HW;
      float* dst0 = &s_rect[w][0];
      if (Wp <= 32) {
        const int act2 = 2 * Wp;
        for (int q2 = 0; q2 < H_f; q2 += 2) {
          const int r = q2 + r_add;
          if (lane < act2 && r < H_f)
            gload_lds4(src + (size_t)r * sz + gx2, dst0 + q2 * Wp);
        }
      } else {
        for (int r = 0; r < H_f; ++r) {
          for (int xc = 0; xc < Wp; xc += 64) {
            const int xxx = xc + lane;
            if (xxx < Wp) {
              const int gx = xxx < W_f - 1 ? xxx : W_f - 1;
              gload_lds4(src + (size_t)r * sz + gx, dst0 + r * Wp + xc);
            }
          }
        }
      }
    }
    __syncthreads();   // drains vmcnt -> rect + (iter 0) meta arrays ready

    if (o < 196) {
      const float* rp = &s_rect[cs][0];
      float acc = 0.0f;
      #pragma unroll
      for (int i = 0; i < 2; ++i) {
        const int sy = 2 * ph + i;
        const int yol = s_ylo[sy], yoh = s_yhi[sy];
        const float fy = s_fy[sy], vy = s_vy[sy];
        #pragma unroll
        for (int j = 0; j < 2; ++j) {
          const int sx = 2 * pw + j;
          const int xl = s_xl[sx];
          const float fx = s_fx[sx], vx = s_vx[sx];
          const float g00 = rp[yol + xl];
          const float g01 = rp[yol + xl + 1];   // pair -> ds_read2_b32
          const float g10 = rp[yoh + xl];
          const float g11 = rp[yoh + xl + 1];
          const float sval = (1.0f - fy) * ((1.0f - fx) * g00 + fx * g01)
                           + fy * ((1.0f - fx) * g10 + fx * g11);
          acc += sval * (vy * vx);
        }
      }
      out[((size_t)k * CCH + c0 + cs) * 49 + bin] = acc * 0.25f;
    }
    __syncthreads();
  }
}

// ---------------- v4 fallback (verified 106us) ----------------
__global__ __launch_bounds__(256) void roi_extract_kernel(
    const float* __restrict__ f0, const float* __restrict__ f1,
    const float* __restrict__ f2, const float* __restrict__ f3,
    const float* __restrict__ rois, float* __restrict__ out, int K)
{
  const int k     = blockIdx.x >> 3;
  const int chunk = blockIdx.x & 7;
  const int t     = threadIdx.x;

  __shared__ int   s_xidx[NG];
  __shared__ int   s_yoff[NG];
  __shared__ float s_fx[NS], s_vx[NS], s_fy[NS], s_vy[NS];
  __shared__ int   s_lvl, s_boff;
  __shared__ float s_grid[8][NG][NG + 1];

  if (t < NG) {
    const float r0 = rois[k*5 + 0];
    const float x1 = rois[k*5 + 1], y1 = rois[k*5 + 2];
    const float x2 = rois[k*5 + 3], y2 = rois[k*5 + 4];
    const float scl = __fsqrt_rn(__fmul_rn(__fsub_rn(x2, x1), __fsub_rn(y2, y1)));
    const float tq  = __fadd_rn(__fdiv_rn(scl, 56.0f), 1e-6f);
    const float lg  = (float)log2((double)tq);
    int lvl = (int)floorf(lg);
    lvl = lvl < 0 ? 0 : (lvl > 3 ? 3 : lvl);
    const int   sizeL = 256 >> lvl;
    const float ssc   = 1.0f / (float)(4 << lvl);
    const int axis = t / NS;
    const int s    = t - axis*NS;
    const float c1 = axis ? y1 : x1;
    const float c2 = axis ? y2 : x2;
    const float start = __fsub_rn(__fmul_rn(c1, ssc), 0.5f);
    const float rlen  = __fmul_rn(__fsub_rn(c2, c1), ssc);
    const float bwid  = __fdiv_rn(rlen, 7.0f);
    const int bin = s >> 1, i = s & 1;
    const float off = ((float)i + 0.5f) * 0.5f;
    const float g = __fadd_rn(__fadd_rn(start, __fmul_rn((float)bin, bwid)),
                              __fmul_rn(off, bwid));
    const float valid = (g >= -1.0f && g <= (float)sizeL) ? 1.0f : 0.0f;
    float cc = fminf(fmaxf(g, 0.0f), (float)(sizeL - 1));
    const int lo0 = (int)floorf(cc);
    int lo, hi; float frac;
    if (lo0 >= sizeL - 1) { lo = sizeL - 1; hi = sizeL - 1; frac = 0.0f; }
    else                  { lo = lo0; hi = lo0 + 1; frac = cc - (float)lo0; }
    if (axis == 0) { s_xidx[s] = lo; s_xidx[NS + s] = hi; s_fx[s] = frac; s_vx[s] = valid; }
    else           { s_yoff[s] = lo * sizeL; s_yoff[NS + s] = hi * sizeL;
                     s_fy[s] = frac; s_vy[s] = valid; }
    if (t == 0) { s_lvl = lvl; s_boff = (int)r0 * CCH * sizeL * sizeL; }
  }
  __syncthreads();

  const int lvl = s_lvl;
  const float* fp = (lvl == 0) ? f0 : (lvl == 1) ? f1 : (lvl == 2) ? f2 : f3;
  const int sz = 256 >> lvl;
  const int HW = sz * sz;
  const float* bp = fp + s_boff;
  const int csub = t >> 5;
  const int lane = t & 31;
  const int xo   = (lane < NG) ? s_xidx[lane] : 0;

  for (int cg = 0; cg < 4; ++cg) {
    const int c0 = chunk * 32 + cg * 8;
    const float* cp = bp + (size_t)(c0 + csub) * HW;
    if (lane < NG) {
      #pragma unroll
      for (int r = 0; r < NG; ++r) s_grid[csub][r][lane] = cp[s_yoff[r] + xo];
    }
    __syncthreads();
    for (int o = t; o < 8 * 49; o += 256) {
      const int cs  = o / 49;
      const int bin = o - cs * 49;
      const int ph  = bin / 7, pw = bin - ph * 7;
      float acc = 0.0f;
      #pragma unroll
      for (int i = 0; i < 2; ++i) {
        const int sy = 2 * ph + i;
        const float fy = s_fy[sy], vy = s_vy[sy];
        #pragma unroll
        for (int j = 0; j < 2; ++j) {
          const int sx = 2 * pw + j;
          const float fx = s_fx[sx], vx = s_vx[sx];
          const float g00 = s_grid[cs][sy][sx];
          const float g01 = s_grid[cs][sy][NS + sx];
          const float g10 = s_grid[cs][NS + sy][sx];
          const float g11 = s_grid[cs][NS + sy][NS + sx];
          const float sval = (1.0f - fy) * ((1.0f - fx) * g00 + fx * g01)
                           + fy * ((1.0f - fx) * g10 + fx * g11);
          acc += sval * (vy * vx);
        }
      }
      out[((size_t)k * CCH + c0 + cs) * 49 + bin] = acc * 0.25f;
    }
    __syncthreads();
  }
}

extern "C" void kernel_launch(void* const* d_in, const int* in_sizes, int n_in,
                              void* d_out, int out_size, void* d_ws, size_t ws_size,
                              hipStream_t stream) {
  const float* f0   = (const float*)d_in[0];
  const float* f1   = (const float*)d_in[1];
  const float* f2   = (const float*)d_in[2];
  const float* f3   = (const float*)d_in[3];
  const float* rois = (const float*)d_in[4];
  float* out = (float*)d_out;
  const int K = in_sizes[4] / 5;

  const size_t need = (size_t)K * MSTRIDE * sizeof(int);
  if (ws_size >= need) {
    int* meta = (int*)d_ws;
    hipLaunchKernelGGL(roi_meta_kernel, dim3((K + 255) / 256), dim3(256), 0, stream,
                       rois, meta, K);
    hipLaunchKernelGGL(roi_rect2_kernel, dim3(K * 8), dim3(256), 0, stream,
                       f0, f1, f2, f3, meta, out);
  } else {
    hipLaunchKernelGGL(roi_extract_kernel, dim3(K * 8), dim3(256), 0, stream,
                       f0, f1, f2, f3, rois, out, K);
  }
}

// Round 10
// 88.672 us; speedup vs baseline: 5.3707x; 1.0745x over previous
//
#include <hip/hip_runtime.h>

// RoIAlign multi-level extractor (FPN), matches jax reference.
//   K=1024 rois, C=256, OUT=7, SR=2, strides {4,8,16,32}, B=2
//
// v6 = v5 + register-hoisted per-bin constants + odd LDS stride.
//   Meta kernel (K threads): exact-fp per-roi metadata (double-log2 level),
//     contiguous rect [x0,x0+W_f) x [y0,y0+H_f), stride Wp = odd >= W_f+1
//     (pad cols edge-dup so pair reads stay in staged data). Rect area bound:
//     rw,rh<=800 & rw*rh<12544 at lvl0 -> Wp*H_f <= ~1080 < RECTMAX=1200.
//   Kernel B (grid K*8): block = (roi, 32-ch chunk); 8 iters of 4 channels.
//     Stage: wave w stages channel c0+w via global_load_lds (no ds_write,
//     no VGPR round-trip; 2 rows/load when Wp<=32).
//     Compute: thread o<196 owns (cs,bin); per-bin offsets and folded
//     weights (incl. validity & 0.25) hoisted to REGISTERS before the loop;
//     inner loop = 8 ds_read2_b32 + 16 FMA + 1 coalesced store.
//   Fallback: v4 kernel (verified 106us) if ws too small.

#define CCH 256
#define NS  14
#define NG  28
#define MSTRIDE 128
#define RECTMAX 1200

__device__ __forceinline__ void gload_lds4(const float* g, float* l) {
  __builtin_amdgcn_global_load_lds(
      (const __attribute__((address_space(1))) void*)g,
      (__attribute__((address_space(3))) void*)l, 4, 0, 0);
}

// ---------------- Kernel A: per-roi metadata ----------------
__global__ __launch_bounds__(256) void roi_meta_kernel(
    const float* __restrict__ rois, int* __restrict__ meta, int K)
{
  const int k = blockIdx.x * 256 + threadIdx.x;
  if (k >= K) return;

  const float r0 = rois[k*5 + 0];
  const float x1 = rois[k*5 + 1], y1 = rois[k*5 + 2];
  const float x2 = rois[k*5 + 3], y2 = rois[k*5 + 4];

  // level: clip(floor(log2(sqrt(w*h)/56 + 1e-6)), 0, 3); f32 op-by-op,
  // log2 via double (matches np.log2 f32 at the binning discontinuities)
  const float scl = __fsqrt_rn(__fmul_rn(__fsub_rn(x2, x1), __fsub_rn(y2, y1)));
  const float tq  = __fadd_rn(__fdiv_rn(scl, 56.0f), 1e-6f);
  const float lg  = (float)log2((double)tq);
  int lvl = (int)floorf(lg);
  lvl = lvl < 0 ? 0 : (lvl > 3 ? 3 : lvl);

  const int   sizeL = 256 >> lvl;
  const float ssc   = 1.0f / (float)(4 << lvl);

  int* m = meta + (size_t)k * MSTRIDE;
  float* mf = (float*)m;
  m[0] = lvl;
  m[1] = (int)r0 * CCH * sizeL * sizeL;

  int lox[NS], hix[NS], loy[NS], hiy[NS];
  float frx[NS], vlx[NS], fry[NS], vly[NS];

  #pragma unroll
  for (int axis = 0; axis < 2; ++axis) {
    const float c1 = axis ? y1 : x1;
    const float c2 = axis ? y2 : x2;
    const float start = __fsub_rn(__fmul_rn(c1, ssc), 0.5f);
    const float rlen  = __fmul_rn(__fsub_rn(c2, c1), ssc);
    const float bwid  = __fdiv_rn(rlen, 7.0f);
    #pragma unroll
    for (int s = 0; s < NS; ++s) {
      const int bin = s >> 1, i = s & 1;
      const float off = ((float)i + 0.5f) * 0.5f;
      const float g = __fadd_rn(__fadd_rn(start, __fmul_rn((float)bin, bwid)),
                                __fmul_rn(off, bwid));
      const float valid = (g >= -1.0f && g <= (float)sizeL) ? 1.0f : 0.0f;
      float cc = fminf(fmaxf(g, 0.0f), (float)(sizeL - 1));
      const int lo0 = (int)floorf(cc);
      int lo, hi; float frac;
      if (lo0 >= sizeL - 1) { lo = sizeL - 1; hi = sizeL - 1; frac = 0.0f; }
      else                  { lo = lo0; hi = lo0 + 1; frac = cc - (float)lo0; }
      if (axis == 0) { lox[s] = lo; hix[s] = hi; frx[s] = frac; vlx[s] = valid; }
      else           { loy[s] = lo; hiy[s] = hi; fry[s] = frac; vly[s] = valid; }
    }
  }

  // g monotone in s -> lo[0] min, hi[13] max
  const int x0  = lox[0];
  const int W_f = hix[NS-1] - x0 + 1;
  int Wp = W_f + 1;                       // pad col (edge dup)
  Wp |= 1;                                // force odd stride (bank spread)
  const int y0  = loy[0];
  const int H_f = hiy[NS-1] - y0 + 1;

  m[2] = x0; m[3] = y0; m[4] = W_f; m[5] = H_f; m[6] = Wp;

  #pragma unroll
  for (int s = 0; s < NS; ++s) {
    m[8 + s]  = lox[s] - x0;            // rect-local x (pair read at +1)
    m[22 + s] = (loy[s] - y0) * Wp;     // rect-local row offsets
    m[36 + s] = (hiy[s] - y0) * Wp;
    mf[50 + s] = frx[s]; mf[64 + s] = vlx[s];
    mf[78 + s] = fry[s]; mf[92 + s] = vly[s];
  }
}

// ---------------- Kernel B: rect-staged, register-hoisted ----------------
__global__ __launch_bounds__(256) void roi_rect2_kernel(
    const float* __restrict__ f0, const float* __restrict__ f1,
    const float* __restrict__ f2, const float* __restrict__ f3,
    const int* __restrict__ meta, float* __restrict__ out)
{
  const int k     = blockIdx.x >> 3;
  const int chunk = blockIdx.x & 7;
  const int t     = threadIdx.x;
  const int w     = t >> 6;            // wave 0..3 stages channel c0+w
  const int lane  = t & 63;

  __shared__ float s_rect[4][RECTMAX];

  const int* m = meta + (size_t)k * MSTRIDE;
  const float* mf = (const float*)m;
  const int lvl  = m[0];
  const int boff = m[1];
  const int x0   = m[2], y0 = m[3];
  const int W_f  = m[4], H_f = m[5], Wp = m[6];
  const float* fp = (lvl == 0) ? f0 : (lvl == 1) ? f1 : (lvl == 2) ? f2 : f3;
  const int sz = 256 >> lvl;
  const int HW = sz * sz;

  // per-lane staging geometry (uniform Wp -> uniform branch)
  const int r_add = (lane >= Wp) ? 1 : 0;       // 2-row packing (Wp<=32)
  const int xx2   = lane - (r_add ? Wp : 0);
  const int gx2   = xx2 < W_f - 1 ? xx2 : W_f - 1;

  // compute decode + per-bin constants -> registers (invariant over iters)
  const int o   = t;                  // o < 196 computes
  const int cs  = o / 49;
  const int bin = o - cs * 49;
  const int ph  = bin / 7;
  const int pw  = bin - ph * 7;

  int   a_lo[4], a_hi[4];
  float w00[4], w01[4], w10[4], w11[4];
  #pragma unroll
  for (int i = 0; i < 2; ++i) {
    const int sy = 2 * ph + i;
    const int yol = m[22 + sy], yoh = m[36 + sy];
    const float fy = mf[78 + sy], vy = mf[92 + sy];
    #pragma unroll
    for (int j = 0; j < 2; ++j) {
      const int sx = 2 * pw + j;
      const int xl = m[8 + sx];
      const float fx = mf[50 + sx], vx = mf[64 + sx];
      const int s4 = 2 * i + j;
      a_lo[s4] = yol + xl;
      a_hi[s4] = yoh + xl;
      const float msk = vy * vx * 0.25f;
      const float wy0 = 1.0f - fy, wy1 = fy;
      const float wx0 = 1.0f - fx, wx1 = fx;
      w00[s4] = wy0 * wx0 * msk;
      w01[s4] = wy0 * wx1 * msk;
      w10[s4] = wy1 * wx0 * msk;
      w11[s4] = wy1 * wx1 * msk;
    }
  }

  const float* base = fp + boff + (size_t)y0 * sz + x0;
  float* outp = out + ((size_t)k * CCH + chunk * 32) * 49 + o;

  for (int it = 0; it < 8; ++it) {
    const int c0 = chunk * 32 + it * 4;
    // ---- stage channel c0+w into s_rect[w] via global_load_lds ----
    {
      const float* src = base + (size_t)(c0 + w) * HW;
      float* dst0 = &s_rect[w][0];
      if (Wp <= 32) {
        const int act2 = 2 * Wp;
        for (int q2 = 0; q2 < H_f; q2 += 2) {
          const int r = q2 + r_add;
          if (lane < act2 && r < H_f)
            gload_lds4(src + (size_t)r * sz + gx2, dst0 + q2 * Wp);
        }
      } else {
        for (int r = 0; r < H_f; ++r) {
          for (int xc = 0; xc < Wp; xc += 64) {
            const int xxx = xc + lane;
            if (xxx < Wp) {
              const int gx = xxx < W_f - 1 ? xxx : W_f - 1;
              gload_lds4(src + (size_t)r * sz + gx, dst0 + r * Wp + xc);
            }
          }
        }
      }
    }
    __syncthreads();   // drains vmcnt -> rect ready

    if (o < 196) {
      const float* rp = &s_rect[cs][0];
      float acc = 0.0f;
      #pragma unroll
      for (int s4 = 0; s4 < 4; ++s4) {
        const float g00 = rp[a_lo[s4]];
        const float g01 = rp[a_lo[s4] + 1];   // pair -> ds_read2_b32
        const float g10 = rp[a_hi[s4]];
        const float g11 = rp[a_hi[s4] + 1];
        acc = __builtin_fmaf(w00[s4], g00, acc);
        acc = __builtin_fmaf(w01[s4], g01, acc);
        acc = __builtin_fmaf(w10[s4], g10, acc);
        acc = __builtin_fmaf(w11[s4], g11, acc);
      }
      *outp = acc;
    }
    outp += 196;
    __syncthreads();
  }
}

// ---------------- v4 fallback (verified 106us) ----------------
__global__ __launch_bounds__(256) void roi_extract_kernel(
    const float* __restrict__ f0, const float* __restrict__ f1,
    const float* __restrict__ f2, const float* __restrict__ f3,
    const float* __restrict__ rois, float* __restrict__ out, int K)
{
  const int k     = blockIdx.x >> 3;
  const int chunk = blockIdx.x & 7;
  const int t     = threadIdx.x;

  __shared__ int   s_xidx[NG];
  __shared__ int   s_yoff[NG];
  __shared__ float s_fx[NS], s_vx[NS], s_fy[NS], s_vy[NS];
  __shared__ int   s_lvl, s_boff;
  __shared__ float s_grid[8][NG][NG + 1];

  if (t < NG) {
    const float r0 = rois[k*5 + 0];
    const float x1 = rois[k*5 + 1], y1 = rois[k*5 + 2];
    const float x2 = rois[k*5 + 3], y2 = rois[k*5 + 4];
    const float scl = __fsqrt_rn(__fmul_rn(__fsub_rn(x2, x1), __fsub_rn(y2, y1)));
    const float tq  = __fadd_rn(__fdiv_rn(scl, 56.0f), 1e-6f);
    const float lg  = (float)log2((double)tq);
    int lvl = (int)floorf(lg);
    lvl = lvl < 0 ? 0 : (lvl > 3 ? 3 : lvl);
    const int   sizeL = 256 >> lvl;
    const float ssc   = 1.0f / (float)(4 << lvl);
    const int axis = t / NS;
    const int s    = t - axis*NS;
    const float c1 = axis ? y1 : x1;
    const float c2 = axis ? y2 : x2;
    const float start = __fsub_rn(__fmul_rn(c1, ssc), 0.5f);
    const float rlen  = __fmul_rn(__fsub_rn(c2, c1), ssc);
    const float bwid  = __fdiv_rn(rlen, 7.0f);
    const int bin = s >> 1, i = s & 1;
    const float off = ((float)i + 0.5f) * 0.5f;
    const float g = __fadd_rn(__fadd_rn(start, __fmul_rn((float)bin, bwid)),
                              __fmul_rn(off, bwid));
    const float valid = (g >= -1.0f && g <= (float)sizeL) ? 1.0f : 0.0f;
    float cc = fminf(fmaxf(g, 0.0f), (float)(sizeL - 1));
    const int lo0 = (int)floorf(cc);
    int lo, hi; float frac;
    if (lo0 >= sizeL - 1) { lo = sizeL - 1; hi = sizeL - 1; frac = 0.0f; }
    else                  { lo = lo0; hi = lo0 + 1; frac = cc - (float)lo0; }
    if (axis == 0) { s_xidx[s] = lo; s_xidx[NS + s] = hi; s_fx[s] = frac; s_vx[s] = valid; }
    else           { s_yoff[s] = lo * sizeL; s_yoff[NS + s] = hi * sizeL;
                     s_fy[s] = frac; s_vy[s] = valid; }
    if (t == 0) { s_lvl = lvl; s_boff = (int)r0 * CCH * sizeL * sizeL; }
  }
  __syncthreads();

  const int lvl = s_lvl;
  const float* fp = (lvl == 0) ? f0 : (lvl == 1) ? f1 : (lvl == 2) ? f2 : f3;
  const int sz = 256 >> lvl;
  const int HW = sz * sz;
  const float* bp = fp + s_boff;
  const int csub = t >> 5;
  const int lane = t & 31;
  const int xo   = (lane < NG) ? s_xidx[lane] : 0;

  for (int cg = 0; cg < 4; ++cg) {
    const int c0 = chunk * 32 + cg * 8;
    const float* cp = bp + (size_t)(c0 + csub) * HW;
    if (lane < NG) {
      #pragma unroll
      for (int r = 0; r < NG; ++r) s_grid[csub][r][lane] = cp[s_yoff[r] + xo];
    }
    __syncthreads();
    for (int o = t; o < 8 * 49; o += 256) {
      const int cs  = o / 49;
      const int bin = o - cs * 49;
      const int ph  = bin / 7, pw = bin - ph * 7;
      float acc = 0.0f;
      #pragma unroll
      for (int i = 0; i < 2; ++i) {
        const int sy = 2 * ph + i;
        const float fy = s_fy[sy], vy = s_vy[sy];
        #pragma unroll
        for (int j = 0; j < 2; ++j) {
          const int sx = 2 * pw + j;
          const float fx = s_fx[sx], vx = s_vx[sx];
          const float g00 = s_grid[cs][sy][sx];
          const float g01 = s_grid[cs][sy][NS + sx];
          const float g10 = s_grid[cs][NS + sy][sx];
          const float g11 = s_grid[cs][NS + sy][NS + sx];
          const float sval = (1.0f - fy) * ((1.0f - fx) * g00 + fx * g01)
                           + fy * ((1.0f - fx) * g10 + fx * g11);
          acc += sval * (vy * vx);
        }
      }
      out[((size_t)k * CCH + c0 + cs) * 49 + bin] = acc * 0.25f;
    }
    __syncthreads();
  }
}

extern "C" void kernel_launch(void* const* d_in, const int* in_sizes, int n_in,
                              void* d_out, int out_size, void* d_ws, size_t ws_size,
                              hipStream_t stream) {
  const float* f0   = (const float*)d_in[0];
  const float* f1   = (const float*)d_in[1];
  const float* f2   = (const float*)d_in[2];
  const float* f3   = (const float*)d_in[3];
  const float* rois = (const float*)d_in[4];
  float* out = (float*)d_out;
  const int K = in_sizes[4] / 5;

  const size_t need = (size_t)K * MSTRIDE * sizeof(int);
  if (ws_size >= need) {
    int* meta = (int*)d_ws;
    hipLaunchKernelGGL(roi_meta_kernel, dim3((K + 255) / 256), dim3(256), 0, stream,
                       rois, meta, K);
    hipLaunchKernelGGL(roi_rect2_kernel, dim3(K * 8), dim3(256), 0, stream,
                       f0, f1, f2, f3, meta, out);
  } else {
    hipLaunchKernelGGL(roi_extract_kernel, dim3(K * 8), dim3(256), 0, stream,
                       f0, f1, f2, f3, rois, out, K);
  }
}